// Round 7
// baseline (109.511 us; speedup 1.0000x reference)
//
#include <hip/hip_runtime.h>
#include <math.h>

#define B_   4
#define N_   512
#define T_   128
#define F_   64
#define QT   128
#define NSTR (T_*F_)   // 8192 floats between consecutive n
#define TILE 8192      // bytes per k-tile: 64n x 64f bf16, blocked layout
// blocked layout: addr(n,f) = (f>>4)*2048 + (n>>2)*128 + (n&3)*32 + (f&15)*2

typedef __attribute__((ext_vector_type(8))) short  s8v;
typedef __attribute__((ext_vector_type(4))) float  f4v;

union F8 { s8v v; unsigned u[4]; uint2 u2[2]; };

__device__ __forceinline__ unsigned cvt_pk(float lo, float hi) {
    unsigned r;
    asm("v_cvt_pk_bf16_f32 %0, %1, %2" : "=v"(r) : "v"(lo), "v"(hi));
    return r;
}

// hardware transpose read: lane l, elem j <- lds[base_e + (l&15) + j*16 + (l>>4)*64]
// (bf16 units), given vaddr = base_byte + lane*8. OFF is a compile-time byte offset.
template<int OFF>
__device__ __forceinline__ uint2 tr16(unsigned a) {
    uint2 d;
    asm volatile("ds_read_b64_tr_b16 %0, %1 offset:%2" : "=v"(d) : "v"(a), "i"(OFF));
    return d;
}

#define EXPK 0.18033688f   // 0.125 * log2(e) : exp(s/8) = exp2(s*EXPK)

__global__ __launch_bounds__(256, 3)
void sgcn_mfma6_kernel(const float* __restrict__ x,
                       const float* __restrict__ adj,
                       const float* __restrict__ theta,
                       float* __restrict__ out)
{
    __shared__ char ldsbuf[2*TILE];   // 16384 B double buffer

    const int tid  = threadIdx.x;
    const int lane = tid & 63;
    const int w    = tid >> 6;       // wave 0..3
    const int c15  = lane & 15;
    const int g4   = lane >> 4;      // 0..3

    const int g  = blockIdx.y;       // group = b*T + t
    const int b  = g >> 7;
    const int t  = g & 127;
    const int q0 = blockIdx.x*QT + 32*w;   // this wave's q-base

    const float* xg = x + (size_t)b*N_*NSTR + (size_t)t*F_;

    // ---- Q as B-fragments (swapped QK: S^T = K * Q^T); f-map: f = 32kk+8g4+j ----
    F8 qf[2][2];   // [qt][kk]
    #pragma unroll
    for (int qt = 0; qt < 2; ++qt)
      #pragma unroll
      for (int kk = 0; kk < 2; ++kk) {
        const float* qp = xg + (size_t)(q0 + 16*qt + c15)*NSTR + 32*kk + 8*g4;
        float4 a = *(const float4*)qp;
        float4 c = *(const float4*)(qp + 4);
        qf[qt][kk].u[0] = cvt_pk(a.x, a.y);
        qf[qt][kk].u[1] = cvt_pk(a.z, a.w);
        qf[qt][kk].u[2] = cvt_pk(c.x, c.y);
        qf[qt][kk].u[3] = cvt_pk(c.z, c.w);
      }

    f4v  Oacc[4][2];   // O^T accumulators [ft][qt]
    float l_acc[2] = {0.f, 0.f};
    #pragma unroll
    for (int ft = 0; ft < 4; ++ft)
      #pragma unroll
      for (int qt = 0; qt < 2; ++qt) Oacc[ft][qt] = (f4v)0.f;

    const int nrow = tid >> 4;       // = 4w + g4 : staging row (+16*it)
    // staging write byte addr for (n = nrow+16it, f0 = 4c15): stoff + it*512
    const int stoff = (c15>>2)*2048 + w*128 + g4*32 + (c15&3)*8;
    // QK A-frag byte addr for (mt, kk): afoff + mt*512 + kk*4096
    //   -> m = 16mt + c15, f = 32kk + 8g4 + j   (matches qf's f-map)
    const int afoff = (g4>>1)*2048 + (c15>>2)*128 + (c15&3)*32 + (g4&1)*16;

    // adj row bases (lane-fixed)
    const float* arow0 = adj + (size_t)(q0 +      c15)*N_ + 4*g4;
    const float* arow1 = adj + (size_t)(q0 + 16 + c15)*N_ + 4*g4;

    auto stage = [&](char* buf, const float4* xvv) {
        #pragma unroll
        for (int it = 0; it < 4; ++it) {
            unsigned p0 = cvt_pk(xvv[it].x, xvv[it].y);
            unsigned p1 = cvt_pk(xvv[it].z, xvv[it].w);
            *(uint2*)(buf + stoff + it*512) = make_uint2(p0, p1);
        }
    };

    // ---- prologue: load + stage k-tile 0 into buffer 0 ----
    float4 xv[4];
    #pragma unroll
    for (int it = 0; it < 4; ++it)
        xv[it] = *(const float4*)(xg + (size_t)(nrow + 16*it)*NSTR + 4*c15);
    stage(ldsbuf, xv);

    const unsigned xb = (unsigned)(uintptr_t)ldsbuf;   // LDS byte offset (gfx9 aperture: low32)

    for (int kt = 0; kt < 8; ++kt) {
        __syncthreads();   // buf[kt&1] staged; reads of buf[kt&1 ^1] done

        char* bufC = ldsbuf + (size_t)(kt & 1) * TILE;
        char* bufN = ldsbuf + (size_t)((kt & 1) ^ 1) * TILE;

        // issue next-tile global loads early (covered by QK+PV compute)
        if (kt < 7) {
            #pragma unroll
            for (int it = 0; it < 4; ++it)
                xv[it] = *(const float4*)(xg + (size_t)((kt+1)*64 + nrow + 16*it)*NSTR + 4*c15);
        }

        // ---- QK^T + softmax, per mt ----
        F8 pb[2][2];   // [qt][kk] PV B-frags; slot j: m = 32kk + 16*(j>=4) + 4g4 + (j&3)
        #pragma unroll
        for (int mt = 0; mt < 4; ++mt) {
            float4 av0 = *(const float4*)(arow0 + kt*64 + 16*mt);
            float4 av1 = *(const float4*)(arow1 + kt*64 + 16*mt);

            F8 af0, af1;   // A: row m = 16mt+c15, k-slot j -> f = 32kk+8g4+j
            af0.v = *(const s8v*)(bufC + afoff + mt*512);
            af1.v = *(const s8v*)(bufC + afoff + mt*512 + 4096);

            #pragma unroll
            for (int qt = 0; qt < 2; ++qt) {
                f4v s = (f4v)0.f;
                s = __builtin_amdgcn_mfma_f32_16x16x32_bf16(af0.v, qf[qt][0].v, s, 0, 0, 0);
                s = __builtin_amdgcn_mfma_f32_16x16x32_bf16(af1.v, qf[qt][1].v, s, 0, 0, 0);
                float e0 = __builtin_amdgcn_exp2f(s[0] * EXPK);
                float e1 = __builtin_amdgcn_exp2f(s[1] * EXPK);
                float e2 = __builtin_amdgcn_exp2f(s[2] * EXPK);
                float e3 = __builtin_amdgcn_exp2f(s[3] * EXPK);
                l_acc[qt] += (e0 + e1) + (e2 + e3);
                float4 av = qt ? av1 : av0;
                pb[qt][mt>>1].u[2*(mt&1)  ] = cvt_pk(e0*av.x, e1*av.y);
                pb[qt][mt>>1].u[2*(mt&1)+1] = cvt_pk(e2*av.z, e3*av.w);
            }
        }

        // ---- PV via hardware transpose reads ----
        // vf slot j: n = 32kk + 16*(j>=4) + 4g4 + (j&3), f = 16ft + c15 (matches pb)
        const unsigned va = xb + (unsigned)((kt & 1) * TILE) + (unsigned)(lane * 8);
        {
            F8 vf0, vf1, vf2, vf3;
            vf0.u2[0] = tr16<   0>(va); vf0.u2[1] = tr16< 512>(va);
            vf1.u2[0] = tr16<2048>(va); vf1.u2[1] = tr16<2560>(va);
            vf2.u2[0] = tr16<4096>(va); vf2.u2[1] = tr16<4608>(va);
            vf3.u2[0] = tr16<6144>(va); vf3.u2[1] = tr16<6656>(va);
            asm volatile("s_waitcnt lgkmcnt(0)" ::: "memory");
            __builtin_amdgcn_sched_barrier(0);
            #pragma unroll
            for (int qt = 0; qt < 2; ++qt) {
                Oacc[0][qt] = __builtin_amdgcn_mfma_f32_16x16x32_bf16(vf0.v, pb[qt][0].v, Oacc[0][qt], 0, 0, 0);
                Oacc[1][qt] = __builtin_amdgcn_mfma_f32_16x16x32_bf16(vf1.v, pb[qt][0].v, Oacc[1][qt], 0, 0, 0);
                Oacc[2][qt] = __builtin_amdgcn_mfma_f32_16x16x32_bf16(vf2.v, pb[qt][0].v, Oacc[2][qt], 0, 0, 0);
                Oacc[3][qt] = __builtin_amdgcn_mfma_f32_16x16x32_bf16(vf3.v, pb[qt][0].v, Oacc[3][qt], 0, 0, 0);
            }
        }
        {
            F8 vf0, vf1, vf2, vf3;
            vf0.u2[0] = tr16<1024>(va); vf0.u2[1] = tr16<1536>(va);
            vf1.u2[0] = tr16<3072>(va); vf1.u2[1] = tr16<3584>(va);
            vf2.u2[0] = tr16<5120>(va); vf2.u2[1] = tr16<5632>(va);
            vf3.u2[0] = tr16<7168>(va); vf3.u2[1] = tr16<7680>(va);
            asm volatile("s_waitcnt lgkmcnt(0)" ::: "memory");
            __builtin_amdgcn_sched_barrier(0);
            #pragma unroll
            for (int qt = 0; qt < 2; ++qt) {
                Oacc[0][qt] = __builtin_amdgcn_mfma_f32_16x16x32_bf16(vf0.v, pb[qt][1].v, Oacc[0][qt], 0, 0, 0);
                Oacc[1][qt] = __builtin_amdgcn_mfma_f32_16x16x32_bf16(vf1.v, pb[qt][1].v, Oacc[1][qt], 0, 0, 0);
                Oacc[2][qt] = __builtin_amdgcn_mfma_f32_16x16x32_bf16(vf2.v, pb[qt][1].v, Oacc[2][qt], 0, 0, 0);
                Oacc[3][qt] = __builtin_amdgcn_mfma_f32_16x16x32_bf16(vf3.v, pb[qt][1].v, Oacc[3][qt], 0, 0, 0);
            }
        }

        // ---- stage next tile into the other buffer (write-late) ----
        if (kt < 7) stage(bufN, xv);
    }

    // ---- softmax denominators ----
    float inv[2];
    #pragma unroll
    for (int qt = 0; qt < 2; ++qt) {
        float lv = l_acc[qt];
        lv += __shfl_xor(lv, 16);
        lv += __shfl_xor(lv, 32);
        inv[qt] = 0.125f / lv;
    }

    // ---- B-frags from O^T (lane-local), scaled ----
    F8 ob[2][2];
    #pragma unroll
    for (int qt = 0; qt < 2; ++qt)
      #pragma unroll
      for (int kk = 0; kk < 2; ++kk) {
        f4v o0 = Oacc[2*kk][qt], o1 = Oacc[2*kk+1][qt];
        ob[qt][kk].u[0] = cvt_pk(o0[0]*inv[qt], o0[1]*inv[qt]);
        ob[qt][kk].u[1] = cvt_pk(o0[2]*inv[qt], o0[3]*inv[qt]);
        ob[qt][kk].u[2] = cvt_pk(o1[0]*inv[qt], o1[1]*inv[qt]);
        ob[qt][kk].u[3] = cvt_pk(o1[2]*inv[qt], o1[3]*inv[qt]);
      }

    // ---- Theta A-frags (same k-permutation as ob) ----
    F8 tf[4][2];
    #pragma unroll
    for (int ot = 0; ot < 4; ++ot)
      #pragma unroll
      for (int kk = 0; kk < 2; ++kk) {
        const float* tp = theta + (size_t)(16*ot + c15)*F_ + 32*kk + 4*g4;
        float4 a = *(const float4*)tp;          // fi = 32kk+4g4 + 0..3
        float4 c = *(const float4*)(tp + 16);   // fi = 32kk+16+4g4 + 0..3
        tf[ot][kk].u[0] = cvt_pk(a.x, a.y);
        tf[ot][kk].u[1] = cvt_pk(a.z, a.w);
        tf[ot][kk].u[2] = cvt_pk(c.x, c.y);
        tf[ot][kk].u[3] = cvt_pk(c.z, c.w);
      }

    // ---- R^T = Theta * (O^T * inv), relu, store ----
    f4v R[4][2];
    #pragma unroll
    for (int ot = 0; ot < 4; ++ot)
      #pragma unroll
      for (int qt = 0; qt < 2; ++qt) R[ot][qt] = (f4v)0.f;

    #pragma unroll
    for (int kk = 0; kk < 2; ++kk)
      #pragma unroll
      for (int ot = 0; ot < 4; ++ot)
        #pragma unroll
        for (int qt = 0; qt < 2; ++qt)
          R[ot][qt] = __builtin_amdgcn_mfma_f32_16x16x32_bf16(tf[ot][kk].v, ob[qt][kk].v, R[ot][qt], 0, 0, 0);

    #pragma unroll
    for (int ot = 0; ot < 4; ++ot)
      #pragma unroll
      for (int qt = 0; qt < 2; ++qt) {
        float4 v;
        v.x = fmaxf(R[ot][qt][0], 0.f);
        v.y = fmaxf(R[ot][qt][1], 0.f);
        v.z = fmaxf(R[ot][qt][2], 0.f);
        v.w = fmaxf(R[ot][qt][3], 0.f);
        int q  = q0 + 16*qt + c15;
        int fo = 16*ot + 4*g4;
        *(float4*)(out + ((size_t)(b*N_ + q)*T_ + t)*F_ + fo) = v;
      }
}

extern "C" void kernel_launch(void* const* d_in, const int* in_sizes, int n_in,
                              void* d_out, int out_size, void* d_ws, size_t ws_size,
                              hipStream_t stream) {
    const float* x     = (const float*)d_in[0];
    const float* adj   = (const float*)d_in[1];
    const float* theta = (const float*)d_in[2];
    float* out = (float*)d_out;

    dim3 grid(N_ / QT, B_ * T_);   // (4, 512) = 2048 blocks
    sgcn_mfma6_kernel<<<grid, 256, 0, stream>>>(x, adj, theta, out);
}